// Round 1
// baseline (3501.863 us; speedup 1.0000x reference)
//
#include <hip/hip_runtime.h>
#include <math.h>

// InstantNGP hash-grid encoder: N=2M points, 16 levels, 2^19-entry tables, 2 feats.
// Round 1: correctness + sane structure. One thread = one point, serial level
// loop (wave-coherent table region per gather), incremental hash, float2
// gathers, LDS-staged coalesced output writes.

#define NLV 16
#define TSZ (1 << 19)
#define TMASK (TSZ - 1)
#define BLK 256
// LDS row = 32 feats + 2 pad floats -> write-stage bank stride 2 (free 2-way),
// rows stay 8B-aligned for float2 access.
#define ROWF 34

struct Res16 { int r[NLV]; };

__global__ __launch_bounds__(BLK) void hashenc_kernel(
    const float* __restrict__ pos,
    const float* __restrict__ tab,
    float* __restrict__ out,
    const Res16 rr, const int npts)
{
    __shared__ float lds[BLK * ROWF];
    const int t = threadIdx.x;
    const long long blk = blockIdx.x;
    const long long n = blk * BLK + t;

    float px = 0.f, py = 0.f, pz = 0.f;
    if (n < npts) {
        px = pos[n * 3 + 0];
        py = pos[n * 3 + 1];
        pz = pos[n * 3 + 2];
    }

    const unsigned P1 = 2654435761u, P2 = 805459861u, P3 = 3674653429u;

    for (int l = 0; l < NLV; ++l) {
        const int res = rr.r[l];
        const float scale = (float)(res - 1);
        // exact mirror of reference fp32 ops: scaled = p*(res-1); floor; w = s-floor
        const float sx = px * scale, sy = py * scale, sz = pz * scale;
        const float fx = floorf(sx), fy = floorf(sy), fz = floorf(sz);
        const float wx = sx - fx, wy = sy - fy, wz = sz - fz;
        const int gx = (int)fx, gy = (int)fy, gz = (int)fz;
        const int rm = res - 1;
        const int x0 = min(max(gx, 0), rm), x1 = min(max(gx + 1, 0), rm);
        const int y0 = min(max(gy, 0), rm), y1 = min(max(gy + 1, 0), rm);
        const int z0 = min(max(gz, 0), rm), z1 = min(max(gz + 1, 0), rm);
        // incremental spatial hash (uint32 wraparound == torch int64 mod 2^19)
        const unsigned hx0 = (unsigned)x0 * P1, hx1 = (unsigned)x1 * P1;
        const unsigned hy0 = (unsigned)y0 * P2, hy1 = (unsigned)y1 * P2;
        const unsigned hz0 = (unsigned)z0 * P3, hz1 = (unsigned)z1 * P3;

        const float2* __restrict__ tl = ((const float2*)tab) + (long long)l * TSZ;
        // corner order matches reference nesting: dx outer, dy mid, dz inner
        const float2 c000 = tl[(hx0 ^ hy0 ^ hz0) & TMASK];
        const float2 c001 = tl[(hx0 ^ hy0 ^ hz1) & TMASK];
        const float2 c010 = tl[(hx0 ^ hy1 ^ hz0) & TMASK];
        const float2 c011 = tl[(hx0 ^ hy1 ^ hz1) & TMASK];
        const float2 c100 = tl[(hx1 ^ hy0 ^ hz0) & TMASK];
        const float2 c101 = tl[(hx1 ^ hy0 ^ hz1) & TMASK];
        const float2 c110 = tl[(hx1 ^ hy1 ^ hz0) & TMASK];
        const float2 c111 = tl[(hx1 ^ hy1 ^ hz1) & TMASK];

        const float ux = 1.f - wx, uy = 1.f - wy, uz = 1.f - wz;
        // product order (x*y)*z matches jnp.prod over last axis
        const float a00 = ux * uy, a01 = ux * wy, a10 = wx * uy, a11 = wx * wy;
        const float w000 = a00 * uz, w001 = a00 * wz;
        const float w010 = a01 * uz, w011 = a01 * wz;
        const float w100 = a10 * uz, w101 = a10 * wz;
        const float w110 = a11 * uz, w111 = a11 * wz;

        float acc0 = c000.x * w000;           float acc1 = c000.y * w000;
        acc0 += c001.x * w001;                acc1 += c001.y * w001;
        acc0 += c010.x * w010;                acc1 += c010.y * w010;
        acc0 += c011.x * w011;                acc1 += c011.y * w011;
        acc0 += c100.x * w100;                acc1 += c100.y * w100;
        acc0 += c101.x * w101;                acc1 += c101.y * w101;
        acc0 += c110.x * w110;                acc1 += c110.y * w110;
        acc0 += c111.x * w111;                acc1 += c111.y * w111;

        lds[t * ROWF + 2 * l + 0] = acc0;
        lds[t * ROWF + 2 * l + 1] = acc1;
    }

    __syncthreads();

    // cooperative coalesced write-out: this block owns a contiguous 32KB of out
    float2* o2 = (float2*)out;
    const float2* l2 = (const float2*)lds;   // row stride 17 float2
    const long long obase = blk * (BLK * 16);
    const long long lim = (long long)npts * 16;
    #pragma unroll
    for (int k = 0; k < 16; ++k) {
        const long long g = obase + (long long)k * BLK + t;
        if (g < lim) {
            const int lp = (int)((g >> 4) - blk * BLK);  // local point
            const int fp = (int)(g & 15);                // float2 within point
            o2[g] = l2[lp * 17 + fp];
        }
    }
}

extern "C" void kernel_launch(void* const* d_in, const int* in_sizes, int n_in,
                              void* d_out, int out_size, void* d_ws, size_t ws_size,
                              hipStream_t stream) {
    const float* pos = (const float*)d_in[0];
    const float* tab = (const float*)d_in[1];
    float* out = (float*)d_out;
    const int npts = in_sizes[0] / 3;

    // Mirror the reference's float64 chain exactly:
    // _B = exp((log(2048)-log(16))/15); res = min(int(16*_B**l), 2048)
    // NOTE: level 15 true value is 2048 within ~1e-12; if validation fails with
    // absmax ~1e-4, numpy's exp rounded the other way -> set rr.r[15] = 2047.
    Res16 rr;
    const double B = exp((log(2048.0) - log(16.0)) / 15.0);
    for (int l = 0; l < NLV; ++l) {
        const double v = 16.0 * pow(B, (double)l);
        int r = (int)v;
        if (r > 2048) r = 2048;
        rr.r[l] = r;
    }

    const int blocks = (npts + BLK - 1) / BLK;
    hipLaunchKernelGGL(hashenc_kernel, dim3(blocks), dim3(BLK), 0, stream,
                       pos, tab, out, rr, npts);
}

// Round 2
// 1453.393 us; speedup vs baseline: 2.4094x; 2.4094x over previous
//
#include <hip/hip_runtime.h>
#include <math.h>

// InstantNGP hash-grid encoder, Round 2: level-phased execution for L2 residency.
// Each level's table (4 MB) == one XCD L2. Grid is level-major so in-flight
// blocks span ~1 level chip-wide -> table replicated in all 8 L2s -> gathers
// hit L2 instead of fabric/L3 (round 1: 12.3 GB FETCH_SIZE, 75% L2 miss).
// Pass 1 writes level-major ws (coalesced), pass 2 LDS-transposes to [N,32].

#define NLV 16
#define TSZ (1 << 19)
#define TMASK (TSZ - 1)
#define BLK 256
#define ROWF 34   // round-1 fallback LDS row stride (floats)

struct Res16 { int r[NLV]; };

__device__ __forceinline__ float2 enc_level(
    const float px, const float py, const float pz,
    const int res, const float2* __restrict__ tl)
{
    const unsigned P1 = 2654435761u, P2 = 805459861u, P3 = 3674653429u;
    const float scale = (float)(res - 1);
    const float sx = px * scale, sy = py * scale, sz = pz * scale;
    const float fx = floorf(sx), fy = floorf(sy), fz = floorf(sz);
    const float wx = sx - fx, wy = sy - fy, wz = sz - fz;
    const int gx = (int)fx, gy = (int)fy, gz = (int)fz;
    const int rm = res - 1;
    const int x0 = min(max(gx, 0), rm), x1 = min(max(gx + 1, 0), rm);
    const int y0 = min(max(gy, 0), rm), y1 = min(max(gy + 1, 0), rm);
    const int z0 = min(max(gz, 0), rm), z1 = min(max(gz + 1, 0), rm);
    const unsigned hx0 = (unsigned)x0 * P1, hx1 = (unsigned)x1 * P1;
    const unsigned hy0 = (unsigned)y0 * P2, hy1 = (unsigned)y1 * P2;
    const unsigned hz0 = (unsigned)z0 * P3, hz1 = (unsigned)z1 * P3;

    const float2 c000 = tl[(hx0 ^ hy0 ^ hz0) & TMASK];
    const float2 c001 = tl[(hx0 ^ hy0 ^ hz1) & TMASK];
    const float2 c010 = tl[(hx0 ^ hy1 ^ hz0) & TMASK];
    const float2 c011 = tl[(hx0 ^ hy1 ^ hz1) & TMASK];
    const float2 c100 = tl[(hx1 ^ hy0 ^ hz0) & TMASK];
    const float2 c101 = tl[(hx1 ^ hy0 ^ hz1) & TMASK];
    const float2 c110 = tl[(hx1 ^ hy1 ^ hz0) & TMASK];
    const float2 c111 = tl[(hx1 ^ hy1 ^ hz1) & TMASK];

    const float ux = 1.f - wx, uy = 1.f - wy, uz = 1.f - wz;
    const float a00 = ux * uy, a01 = ux * wy, a10 = wx * uy, a11 = wx * wy;
    const float w000 = a00 * uz, w001 = a00 * wz;
    const float w010 = a01 * uz, w011 = a01 * wz;
    const float w100 = a10 * uz, w101 = a10 * wz;
    const float w110 = a11 * uz, w111 = a11 * wz;

    float acc0 = c000.x * w000;           float acc1 = c000.y * w000;
    acc0 += c001.x * w001;                acc1 += c001.y * w001;
    acc0 += c010.x * w010;                acc1 += c010.y * w010;
    acc0 += c011.x * w011;                acc1 += c011.y * w011;
    acc0 += c100.x * w100;                acc1 += c100.y * w100;
    acc0 += c101.x * w101;                acc1 += c101.y * w101;
    acc0 += c110.x * w110;                acc1 += c110.y * w110;
    acc0 += c111.x * w111;                acc1 += c111.y * w111;
    return make_float2(acc0, acc1);
}

// ---------------- Pass 1: level-major gather, coalesced ws write ----------------
__global__ __launch_bounds__(BLK) void pass1_kernel(
    const float* __restrict__ pos,
    const float* __restrict__ tab,
    float2* __restrict__ ws2,          // [NLV][npts] float2, level-major
    const Res16 rr, const int npts, const int nblk_per_level)
{
    const int level = blockIdx.x / nblk_per_level;
    const int chunk = blockIdx.x % nblk_per_level;
    const long long n = (long long)chunk * BLK + threadIdx.x;
    if (n >= npts) return;

    const float px = pos[n * 3 + 0];
    const float py = pos[n * 3 + 1];
    const float pz = pos[n * 3 + 2];

    const float2* tl = ((const float2*)tab) + (long long)level * TSZ;
    const float2 f = enc_level(px, py, pz, rr.r[level], tl);
    ws2[(long long)level * npts + n] = f;
}

// ---------------- Pass 2: transpose [L][N]f2 -> [N][L]f2 via LDS ----------------
__global__ __launch_bounds__(BLK) void pass2_kernel(
    const float2* __restrict__ ws2,
    float4* __restrict__ out4,         // out viewed as [npts][8] float4
    const int npts)
{
    __shared__ float2 l2s[BLK][NLV + 2];   // stride 18 f2 = 144 B, 16B-aligned rows
    const int t = threadIdx.x;
    const long long p0 = (long long)blockIdx.x * BLK;
    const long long n = p0 + t;

    #pragma unroll
    for (int l = 0; l < NLV; ++l) {
        float2 v = make_float2(0.f, 0.f);
        if (n < npts) v = ws2[(long long)l * npts + n];
        l2s[t][l] = v;
    }
    __syncthreads();

    // 2048 float4 chunks per block (256 points x 8), contiguous global writes
    #pragma unroll
    for (int k = 0; k < 8; ++k) {
        const int idx = k * BLK + t;
        const int pt = idx >> 3;
        const int q = idx & 7;
        const long long np = p0 + pt;
        if (np < npts) {
            out4[np * 8 + q] = *(const float4*)&l2s[pt][q * 2];
        }
    }
}

// ---------------- Fallback (ws too small): round-1 fused kernel ----------------
__global__ __launch_bounds__(BLK) void fused_kernel(
    const float* __restrict__ pos,
    const float* __restrict__ tab,
    float* __restrict__ out,
    const Res16 rr, const int npts)
{
    __shared__ float lds[BLK * ROWF];
    const int t = threadIdx.x;
    const long long blk = blockIdx.x;
    const long long n = blk * BLK + t;

    float px = 0.f, py = 0.f, pz = 0.f;
    if (n < npts) {
        px = pos[n * 3 + 0];
        py = pos[n * 3 + 1];
        pz = pos[n * 3 + 2];
    }
    for (int l = 0; l < NLV; ++l) {
        const float2* tl = ((const float2*)tab) + (long long)l * TSZ;
        const float2 f = enc_level(px, py, pz, rr.r[l], tl);
        lds[t * ROWF + 2 * l + 0] = f.x;
        lds[t * ROWF + 2 * l + 1] = f.y;
    }
    __syncthreads();
    float2* o2 = (float2*)out;
    const float2* l2 = (const float2*)lds;
    const long long obase = blk * (BLK * 16);
    const long long lim = (long long)npts * 16;
    #pragma unroll
    for (int k = 0; k < 16; ++k) {
        const long long g = obase + (long long)k * BLK + t;
        if (g < lim) {
            const int lp = (int)((g >> 4) - blk * BLK);
            const int fp = (int)(g & 15);
            o2[g] = l2[lp * 17 + fp];
        }
    }
}

extern "C" void kernel_launch(void* const* d_in, const int* in_sizes, int n_in,
                              void* d_out, int out_size, void* d_ws, size_t ws_size,
                              hipStream_t stream) {
    const float* pos = (const float*)d_in[0];
    const float* tab = (const float*)d_in[1];
    float* out = (float*)d_out;
    const int npts = in_sizes[0] / 3;

    // Mirror reference float64 chain: _B = exp((log(2048)-log(16))/15);
    // res = min(int(16*_B**l), 2048)
    Res16 rr;
    const double B = exp((log(2048.0) - log(16.0)) / 15.0);
    for (int l = 0; l < NLV; ++l) {
        const double v = 16.0 * pow(B, (double)l);
        int r = (int)v;
        if (r > 2048) r = 2048;
        rr.r[l] = r;
    }

    const size_t ws_needed = (size_t)NLV * npts * sizeof(float2);
    const int nblk = (npts + BLK - 1) / BLK;

    if (ws_size >= ws_needed) {
        float2* ws2 = (float2*)d_ws;
        hipLaunchKernelGGL(pass1_kernel, dim3(nblk * NLV), dim3(BLK), 0, stream,
                           pos, tab, ws2, rr, npts, nblk);
        hipLaunchKernelGGL(pass2_kernel, dim3(nblk), dim3(BLK), 0, stream,
                           ws2, (float4*)out, npts);
    } else {
        hipLaunchKernelGGL(fused_kernel, dim3(nblk), dim3(BLK), 0, stream,
                           pos, tab, out, rr, npts);
    }
}